// Round 6
// baseline (114.841 us; speedup 1.0000x reference)
//
#include <hip/hip_runtime.h>
#include <math.h>

#define BLK 256
#define UB  4   // batches per thread

// ---------------------------------------------------------------------------
// Rotated-box intersection area via Green's theorem (no polygon clipping):
// area(P∩Q) = 1/2 ∮ (x dy − y dx) = Σ P-edge pieces clipped to Q's AAB frame
// + Σ Q-edge pieces clipped to P's AAB frame + 1/2·cross(t, R·ΣΔ) translation
// correction (x dy − y dx is rotation-invariant).  Each piece is a branchless
// Liang-Barsky slab clip; empty clips give exactly-zero-length pieces.
//
// Reciprocal collapse: edge dirs are (±dx·cd, ±dx·sd) and (∓dy·sd, ±dy·cd),
// so all 8 slab reciprocals are products of 6 base rcps:
//   1/dx1, 1/dy1, 1/dx2, 1/dy2, 1/clamp(cd), 1/clamp(sd)
// (dx,dy = exp(..)·anchor_dim > 0: no clamp needed; cd,sd clamped to ±1e-30).
//
// Each thread handles the SAME anchor row for UB=4 batches: anchor load +
// diag amortized x4; all global loads issued up front for memory-level
// parallelism; wave count / launch overhead cut x4.
// ---------------------------------------------------------------------------

__device__ __forceinline__ float clamp_mag(float x) {
    return copysignf(fmaxf(fabsf(x), 1e-30f), x);
}

// clip segment p + s*e, s in [0,1], to box [-hx,hx] x [-hy,hy]; r = 1/e
__device__ __forceinline__ void edge_piece(float px, float py, float ex, float ey,
                                           float rx, float ry, float hx, float hy,
                                           float& area2, float& Dx, float& Dy)
{
    float sx0 = (-hx - px) * rx, sx1 = (hx - px) * rx;
    float sy0 = (-hy - py) * ry, sy1 = (hy - py) * ry;
    float smin = fmaxf(fmaxf(fminf(sx0, sx1), fminf(sy0, sy1)), 0.0f);
    float smax = fminf(fminf(fmaxf(sx0, sx1), fmaxf(sy0, sy1)), 1.0f);
    smax = fmaxf(smax, smin);                  // empty -> zero-length at smin
    float ax = fmaf(smin, ex, px), ay = fmaf(smin, ey, py);
    float bx = fmaf(smax, ex, px), by = fmaf(smax, ey, py);
    float ux = bx - ax, uy = by - ay;          // exactly 0 when smin==smax
    area2 += fmaf(ax, uy, -(ay * ux));         // cross(a, b-a) == cross(a,b)
    Dx += ux; Dy += uy;
}

// Full pair IoU -> loss for one (pred, target) box pair sharing an anchor.
__device__ __forceinline__ float pair_loss(const float bp[5], const float rt[5],
                                           float xa, float ya, float dxa, float dya,
                                           float ra, float diag,
                                           float ip, int oh, float w)
{
    // decode P (pred) / Q (target): fields {x, y, dx, dy, r}
    float x1  = fmaf(bp[0], diag, xa);
    float y1  = fmaf(bp[1], diag, ya);
    float dx1 = __expf(bp[2]) * dxa;
    float dy1 = __expf(bp[3]) * dya;
    float r1  = bp[4] + ra;

    float x2  = fmaf(rt[0], diag, xa);
    float y2  = fmaf(rt[1], diag, ya);
    float dx2 = __expf(rt[2]) * dxa;
    float dy2 = __expf(rt[3]) * dya;
    float r2  = rt[4] + ra;

    float a1 = dx1 * dy1, a2 = dx2 * dy2;
    float h1x = 0.5f * dx1, h1y = 0.5f * dy1;
    float h2x = 0.5f * dx2, h2y = 0.5f * dy2;

    // P in Q's frame: p_Q = R(dr)·p_P + t
    float c2v = __cosf(r2), s2v = __sinf(r2);
    float dr  = r1 - r2;
    float cd  = __cosf(dr), sd = __sinf(dr);
    float ddx = x1 - x2, ddy = y1 - y2;
    float tx  = fmaf(c2v, ddx,  s2v * ddy);
    float ty  = fmaf(-s2v, ddx, c2v * ddy);

    // 6 base reciprocals -> all 8 slab reciprocals by products
    float rcd  = __fdividef(1.0f, clamp_mag(cd));
    float rsd  = __fdividef(1.0f, clamp_mag(sd));
    float rdx1 = __fdividef(1.0f, dx1);
    float rdy1 = __fdividef(1.0f, dy1);
    float rdx2 = __fdividef(1.0f, dx2);
    float rdy2 = __fdividef(1.0f, dy2);

    // P half-edge vectors in Q frame; full edges are ±2u, ±2v
    float ux_ = h1x * cd,  uy_ = h1x * sd;
    float vx_ = -h1y * sd, vy_ = h1y * cd;
    float eux = dx1 * cd,  euy = dx1 * sd;     // 2u
    float evx = -dy1 * sd, evy = dy1 * cd;     // 2v
    float ruxP = rdx1 * rcd,    ruyP = rdx1 * rsd;
    float rvxP = -(rdy1 * rsd), rvyP = rdy1 * rcd;
    // corners (CCW)
    float p0x = tx + ux_ + vx_, p0y = ty + uy_ + vy_;
    float p1x = tx - ux_ + vx_, p1y = ty - uy_ + vy_;
    float p2x = tx - ux_ - vx_, p2y = ty - uy_ - vy_;
    float p3x = tx + ux_ - vx_, p3y = ty + uy_ - vy_;

    float area2 = 0.0f, dDx = 0.0f, dDy = 0.0f;
    edge_piece(p0x, p0y, -eux, -euy, -ruxP, -ruyP, h2x, h2y, area2, dDx, dDy);
    edge_piece(p1x, p1y, -evx, -evy, -rvxP, -rvyP, h2x, h2y, area2, dDx, dDy);
    edge_piece(p2x, p2y,  eux,  euy,  ruxP,  ruyP, h2x, h2y, area2, dDx, dDy);
    edge_piece(p3x, p3y,  evx,  evy,  rvxP,  rvyP, h2x, h2y, area2, dDx, dDy);

    // Q in P's frame: u' = R^T·(h2x,0), v' = R^T·(0,h2y), o = -R^T·t
    float upx = h2x * cd,  upy = -h2x * sd;
    float vpx = h2y * sd,  vpy = h2y * cd;
    float ox  = -(fmaf(cd, tx,  sd * ty));
    float oy  = -(fmaf(-sd, tx, cd * ty));
    float equx = dx2 * cd, equy = -dx2 * sd;
    float eqvx = dy2 * sd, eqvy = dy2 * cd;
    float ruxQ = rdx2 * rcd, ruyQ = -(rdx2 * rsd);
    float rvxQ = rdy2 * rsd, rvyQ = rdy2 * rcd;
    float q0x = ox + upx + vpx, q0y = oy + upy + vpy;
    float q1x = ox - upx + vpx, q1y = oy - upy + vpy;
    float q2x = ox - upx - vpx, q2y = oy - upy - vpy;
    float q3x = ox + upx - vpx, q3y = oy + upy - vpy;

    float Dx = 0.0f, Dy = 0.0f;
    edge_piece(q0x, q0y, -equx, -equy, -ruxQ, -ruyQ, h1x, h1y, area2, Dx, Dy);
    edge_piece(q1x, q1y, -eqvx, -eqvy, -rvxQ, -rvyQ, h1x, h1y, area2, Dx, Dy);
    edge_piece(q2x, q2y,  equx,  equy,  ruxQ,  ruyQ, h1x, h1y, area2, Dx, Dy);
    edge_piece(q3x, q3y,  eqvx,  eqvy,  rvxQ,  rvyQ, h1x, h1y, area2, Dx, Dy);

    // translation correction: cross(t, R·D)
    float RDx = fmaf(cd, Dx, -(sd * Dy));
    float RDy = fmaf(sd, Dx,   cd * Dy);
    area2 += fmaf(tx, RDy, -(ty * RDx));

    float inter = 0.5f * fabsf(area2);
    float uni = fmaxf(a1 + a2 - inter, 1e-6f);
    float iou = __fdividef(inter, uni);

    float target = (oh > 0) ? iou : 0.0f;
    float z  = __fdividef(1.0f, 1.0f + __expf(-ip));   // sigmoid
    float pt = __logf(1.0f + __expf(z)) - z * target;  // logaddexp(0,z) - z*target
    return pt * w;
}

__global__ __launch_bounds__(BLK)
void iou_pred_loss_kernel(const float* __restrict__ iou_preds,
                          const int*   __restrict__ one_hot,
                          const float* __restrict__ weights,
                          const float* __restrict__ anchors,
                          const float* __restrict__ box_preds,
                          const float* __restrict__ reg_targets,
                          float* __restrict__ out,
                          int N, int B)
{
    int tid   = threadIdx.x;
    int n_idx = blockIdx.x * BLK + tid;
    if (n_idx >= N) return;

    int yspan = gridDim.y;                 // = ceil(B/UB)
    size_t g[UB];
    bool   has[UB];
#pragma unroll
    for (int k = 0; k < UB; ++k) {
        int b  = blockIdx.y + k * yspan;
        has[k] = (b < B);
        g[k]   = (size_t)(has[k] ? b : 0) * N + n_idx;
    }

    // ---- issue ALL global loads up front (MLP) ----
    const float* an = anchors + (size_t)n_idx * 7;
    float xa = an[0], ya = an[1], dxa = an[3], dya = an[4], ra = an[6];

    float bp[UB][5], rt[UB][5], ip[UB], w[UB];
    int   oh[UB];
#pragma unroll
    for (int k = 0; k < UB; ++k) {
        const float* bpp = box_preds   + g[k] * 7;
        const float* rtp = reg_targets + g[k] * 7;
        bp[k][0] = bpp[0]; bp[k][1] = bpp[1]; bp[k][2] = bpp[3];
        bp[k][3] = bpp[4]; bp[k][4] = bpp[6];
        rt[k][0] = rtp[0]; rt[k][1] = rtp[1]; rt[k][2] = rtp[3];
        rt[k][3] = rtp[4]; rt[k][4] = rtp[6];
        ip[k] = iou_preds[g[k]];
        oh[k] = one_hot[g[k]];
        w[k]  = weights[g[k]];
    }

    float diag = sqrtf(fmaf(dxa, dxa, dya * dya));

#pragma unroll
    for (int k = 0; k < UB; ++k) {
        float res = pair_loss(bp[k], rt[k], xa, ya, dxa, dya, ra, diag,
                              ip[k], oh[k], w[k]);
        if (has[k]) out[g[k]] = res;
    }
}

extern "C" void kernel_launch(void* const* d_in, const int* in_sizes, int n_in,
                              void* d_out, int out_size, void* d_ws, size_t ws_size,
                              hipStream_t stream) {
    const float* iou_preds   = (const float*)d_in[0];
    const int*   one_hot     = (const int*)  d_in[1];
    const float* weights     = (const float*)d_in[2];
    const float* anchors     = (const float*)d_in[3];
    const float* box_preds   = (const float*)d_in[4];
    const float* reg_targets = (const float*)d_in[5];
    float* out = (float*)d_out;

    int total = in_sizes[0];       // B*N
    int N     = in_sizes[3] / 7;   // anchor count
    int B     = total / N;

    dim3 grid((N + BLK - 1) / BLK, (B + UB - 1) / UB);
    iou_pred_loss_kernel<<<grid, dim3(BLK), 0, stream>>>(
        iou_preds, one_hot, weights, anchors, box_preds, reg_targets,
        out, N, B);
}

// Round 7
// 112.369 us; speedup vs baseline: 1.0220x; 1.0220x over previous
//
#include <hip/hip_runtime.h>
#include <math.h>

#define BLK 256

// ---------------------------------------------------------------------------
// Rotated-box intersection area via Green's theorem (no polygon clipping):
// area(P∩Q) = 1/2 ∮ (x dy − y dx) = Σ P-edge pieces clipped to Q's AAB frame
// + Σ Q-edge pieces clipped to P's AAB frame + 1/2·cross(t, R·ΣΔ) translation
// correction (x dy − y dx is rotation-invariant).  Each piece is a branchless
// Liang-Barsky slab clip; empty clips give exactly-zero-length pieces.
//
// Reciprocal collapse: edge dirs are (±dx·cd, ±dx·sd) and (∓dy·sd, ±dy·cd),
// so all 8 slab reciprocals are products of 6 base rcps:
//   1/dx1, 1/dy1, 1/dx2, 1/dy2, 1/clamp(cd), 1/clamp(sd)
// (dx,dy = exp(..)·anchor_dim > 0: no clamp needed; cd,sd clamped to ±1e-30).
//
// UB=2 batches/thread (UB=4 regressed: +3.2 µs from register pressure —
// round 6).  Anchor load + diag amortized x2; both batches' global loads
// issued up front for MLP.
// ---------------------------------------------------------------------------

__device__ __forceinline__ float clamp_mag(float x) {
    return copysignf(fmaxf(fabsf(x), 1e-30f), x);
}

// clip segment p + s*e, s in [0,1], to box [-hx,hx] x [-hy,hy]; r = 1/e
__device__ __forceinline__ void edge_piece(float px, float py, float ex, float ey,
                                           float rx, float ry, float hx, float hy,
                                           float& area2, float& Dx, float& Dy)
{
    float sx0 = (-hx - px) * rx, sx1 = (hx - px) * rx;
    float sy0 = (-hy - py) * ry, sy1 = (hy - py) * ry;
    float smin = fmaxf(fmaxf(fminf(sx0, sx1), fminf(sy0, sy1)), 0.0f);
    float smax = fminf(fminf(fmaxf(sx0, sx1), fmaxf(sy0, sy1)), 1.0f);
    smax = fmaxf(smax, smin);                  // empty -> zero-length at smin
    float ax = fmaf(smin, ex, px), ay = fmaf(smin, ey, py);
    float bx = fmaf(smax, ex, px), by = fmaf(smax, ey, py);
    float ux = bx - ax, uy = by - ay;          // exactly 0 when smin==smax
    area2 += fmaf(ax, uy, -(ay * ux));         // cross(a, b-a) == cross(a,b)
    Dx += ux; Dy += uy;
}

// Full pair IoU -> loss for one (pred, target) box pair sharing an anchor.
__device__ __forceinline__ float pair_loss(const float bp[5], const float rt[5],
                                           float xa, float ya, float dxa, float dya,
                                           float ra, float diag,
                                           float ip, int oh, float w)
{
    // decode P (pred) / Q (target): fields {x, y, dx, dy, r}
    float x1  = fmaf(bp[0], diag, xa);
    float y1  = fmaf(bp[1], diag, ya);
    float dx1 = __expf(bp[2]) * dxa;
    float dy1 = __expf(bp[3]) * dya;
    float r1  = bp[4] + ra;

    float x2  = fmaf(rt[0], diag, xa);
    float y2  = fmaf(rt[1], diag, ya);
    float dx2 = __expf(rt[2]) * dxa;
    float dy2 = __expf(rt[3]) * dya;
    float r2  = rt[4] + ra;

    float a1 = dx1 * dy1, a2 = dx2 * dy2;
    float h1x = 0.5f * dx1, h1y = 0.5f * dy1;
    float h2x = 0.5f * dx2, h2y = 0.5f * dy2;

    // P in Q's frame: p_Q = R(dr)·p_P + t
    float c2v = __cosf(r2), s2v = __sinf(r2);
    float dr  = r1 - r2;
    float cd  = __cosf(dr), sd = __sinf(dr);
    float ddx = x1 - x2, ddy = y1 - y2;
    float tx  = fmaf(c2v, ddx,  s2v * ddy);
    float ty  = fmaf(-s2v, ddx, c2v * ddy);

    // 6 base reciprocals -> all 8 slab reciprocals by products
    float rcd  = __fdividef(1.0f, clamp_mag(cd));
    float rsd  = __fdividef(1.0f, clamp_mag(sd));
    float rdx1 = __fdividef(1.0f, dx1);
    float rdy1 = __fdividef(1.0f, dy1);
    float rdx2 = __fdividef(1.0f, dx2);
    float rdy2 = __fdividef(1.0f, dy2);

    // P half-edge vectors in Q frame; full edges are ±2u, ±2v
    float ux_ = h1x * cd,  uy_ = h1x * sd;
    float vx_ = -h1y * sd, vy_ = h1y * cd;
    float eux = dx1 * cd,  euy = dx1 * sd;     // 2u
    float evx = -dy1 * sd, evy = dy1 * cd;     // 2v
    float ruxP = rdx1 * rcd,    ruyP = rdx1 * rsd;
    float rvxP = -(rdy1 * rsd), rvyP = rdy1 * rcd;
    // corners (CCW)
    float p0x = tx + ux_ + vx_, p0y = ty + uy_ + vy_;
    float p1x = tx - ux_ + vx_, p1y = ty - uy_ + vy_;
    float p2x = tx - ux_ - vx_, p2y = ty - uy_ - vy_;
    float p3x = tx + ux_ - vx_, p3y = ty + uy_ - vy_;

    float area2 = 0.0f, dDx = 0.0f, dDy = 0.0f;
    edge_piece(p0x, p0y, -eux, -euy, -ruxP, -ruyP, h2x, h2y, area2, dDx, dDy);
    edge_piece(p1x, p1y, -evx, -evy, -rvxP, -rvyP, h2x, h2y, area2, dDx, dDy);
    edge_piece(p2x, p2y,  eux,  euy,  ruxP,  ruyP, h2x, h2y, area2, dDx, dDy);
    edge_piece(p3x, p3y,  evx,  evy,  rvxP,  rvyP, h2x, h2y, area2, dDx, dDy);

    // Q in P's frame: u' = R^T·(h2x,0), v' = R^T·(0,h2y), o = -R^T·t
    float upx = h2x * cd,  upy = -h2x * sd;
    float vpx = h2y * sd,  vpy = h2y * cd;
    float ox  = -(fmaf(cd, tx,  sd * ty));
    float oy  = -(fmaf(-sd, tx, cd * ty));
    float equx = dx2 * cd, equy = -dx2 * sd;
    float eqvx = dy2 * sd, eqvy = dy2 * cd;
    float ruxQ = rdx2 * rcd, ruyQ = -(rdx2 * rsd);
    float rvxQ = rdy2 * rsd, rvyQ = rdy2 * rcd;
    float q0x = ox + upx + vpx, q0y = oy + upy + vpy;
    float q1x = ox - upx + vpx, q1y = oy - upy + vpy;
    float q2x = ox - upx - vpx, q2y = oy - upy - vpy;
    float q3x = ox + upx - vpx, q3y = oy + upy - vpy;

    float Dx = 0.0f, Dy = 0.0f;
    edge_piece(q0x, q0y, -equx, -equy, -ruxQ, -ruyQ, h1x, h1y, area2, Dx, Dy);
    edge_piece(q1x, q1y, -eqvx, -eqvy, -rvxQ, -rvyQ, h1x, h1y, area2, Dx, Dy);
    edge_piece(q2x, q2y,  equx,  equy,  ruxQ,  ruyQ, h1x, h1y, area2, Dx, Dy);
    edge_piece(q3x, q3y,  eqvx,  eqvy,  rvxQ,  rvyQ, h1x, h1y, area2, Dx, Dy);

    // translation correction: cross(t, R·D)
    float RDx = fmaf(cd, Dx, -(sd * Dy));
    float RDy = fmaf(sd, Dx,   cd * Dy);
    area2 += fmaf(tx, RDy, -(ty * RDx));

    float inter = 0.5f * fabsf(area2);
    float uni = fmaxf(a1 + a2 - inter, 1e-6f);
    float iou = __fdividef(inter, uni);

    float target = (oh > 0) ? iou : 0.0f;
    float z  = __fdividef(1.0f, 1.0f + __expf(-ip));   // sigmoid
    float pt = __logf(1.0f + __expf(z)) - z * target;  // logaddexp(0,z) - z*target
    return pt * w;
}

__global__ __launch_bounds__(BLK)
void iou_pred_loss_kernel(const float* __restrict__ iou_preds,
                          const int*   __restrict__ one_hot,
                          const float* __restrict__ weights,
                          const float* __restrict__ anchors,
                          const float* __restrict__ box_preds,
                          const float* __restrict__ reg_targets,
                          float* __restrict__ out,
                          int N, int B)
{
    int tid   = threadIdx.x;
    int n_idx = blockIdx.x * BLK + tid;
    if (n_idx >= N) return;

    int yspan = gridDim.y;                 // = ceil(B/2)
    int b0 = blockIdx.y;
    int b1 = blockIdx.y + yspan;
    bool has2 = (b1 < B);
    size_t g0 = (size_t)b0 * N + n_idx;
    size_t g1 = (size_t)(has2 ? b1 : b0) * N + n_idx;

    // ---- issue ALL global loads up front (MLP) ----
    const float* an = anchors + (size_t)n_idx * 7;
    float xa = an[0], ya = an[1], dxa = an[3], dya = an[4], ra = an[6];

    const float* bpp0 = box_preds   + g0 * 7;
    const float* rtp0 = reg_targets + g0 * 7;
    const float* bpp1 = box_preds   + g1 * 7;
    const float* rtp1 = reg_targets + g1 * 7;
    float bp0[5] = {bpp0[0], bpp0[1], bpp0[3], bpp0[4], bpp0[6]};
    float rt0[5] = {rtp0[0], rtp0[1], rtp0[3], rtp0[4], rtp0[6]};
    float bp1[5] = {bpp1[0], bpp1[1], bpp1[3], bpp1[4], bpp1[6]};
    float rt1[5] = {rtp1[0], rtp1[1], rtp1[3], rtp1[4], rtp1[6]};
    float ip0 = iou_preds[g0], ip1 = iou_preds[g1];
    int   oh0 = one_hot[g0],   oh1 = one_hot[g1];
    float w0  = weights[g0],   w1  = weights[g1];

    float diag = sqrtf(fmaf(dxa, dxa, dya * dya));

    out[g0] = pair_loss(bp0, rt0, xa, ya, dxa, dya, ra, diag, ip0, oh0, w0);
    if (has2)
        out[g1] = pair_loss(bp1, rt1, xa, ya, dxa, dya, ra, diag, ip1, oh1, w1);
}

extern "C" void kernel_launch(void* const* d_in, const int* in_sizes, int n_in,
                              void* d_out, int out_size, void* d_ws, size_t ws_size,
                              hipStream_t stream) {
    const float* iou_preds   = (const float*)d_in[0];
    const int*   one_hot     = (const int*)  d_in[1];
    const float* weights     = (const float*)d_in[2];
    const float* anchors     = (const float*)d_in[3];
    const float* box_preds   = (const float*)d_in[4];
    const float* reg_targets = (const float*)d_in[5];
    float* out = (float*)d_out;

    int total = in_sizes[0];       // B*N
    int N     = in_sizes[3] / 7;   // anchor count
    int B     = total / N;

    dim3 grid((N + BLK - 1) / BLK, (B + 1) / 2);
    iou_pred_loss_kernel<<<grid, dim3(BLK), 0, stream>>>(
        iou_preds, one_hot, weights, anchors, box_preds, reg_targets,
        out, N, B);
}